// Round 1
// 94.092 us; speedup vs baseline: 1.0121x; 1.0121x over previous
//
#include <hip/hip_runtime.h>

// out[b,o,i,j] = sum_c | sum_{ti,tj<=8} K[o,0,ti,tj] * x[b,c,(i+5-ti)&127,(j+5-tj)&127] |
// B=8 C=16 H=W=128 O=32.
// R15 = R14 core, FUSED single kernel, ZERO workspace usage.
//   Hypothesis under test: the two 256MB fillBufferAligned dispatches (~45us
//   each, 74% HBM peak) in the timed region are d_ws re-poison; prep+conv are
//   provably <44.8us each (absent from top-5) yet dur_us=95 > their sum bound.
//   Eliminating all d_ws use should drop dur_us to ~6-12us if the poison is
//   usage-conditional.
// Changes vs R14:
//   - prep kernel deleted; xr global intermediate deleted.
//   - x staging: per-thread incremental (ch,rw,d) walk, 45 iters; bf16 RNE
//     convert + column-reverse (elem e = x[(132-e)&127]) straight into the
//     SAME 288B/row, 11-slot/channel LDS layout (slot 0 unused, slots 1..10 =
//     window rows i0-3..i0+6 mod 128). Byte-identical to what gload_lds
//     staged from xr in R14.
//   - B frags: kern c0-slice (32x81 f32, 10.4KB) coalesced into LDS, then
//     per-lane frag build identical math to prep's bpre (f2bf on same f32
//     values -> bit-identical fragments).
//   - MFMA core, A-frag alignbit extraction, cg-reduce + stride-129 epilogue:
//     verbatim R14.
//   Correctness tell: absmax == 0.0625.

typedef __attribute__((ext_vector_type(8)))  short  short8;
typedef __attribute__((ext_vector_type(16))) float  float16v;
typedef __attribute__((ext_vector_type(4)))  float  float4v;
typedef __attribute__((ext_vector_type(4)))  unsigned int uint4v;

#define CHB 3168                      // LDS bytes per channel (11 rows x 288)

__device__ __forceinline__ unsigned int f2bf(float f) {
    union { float f; unsigned int u; } a; a.f = f;
    unsigned int u = a.u;
    u += 0x7fffu + ((u >> 16) & 1u);   // RNE
    return u >> 16;
}

#if __has_builtin(__builtin_amdgcn_alignbit)
#define ALIGN16(hi_, lo_) __builtin_amdgcn_alignbit((hi_), (lo_), 16)
#else
#define ALIGN16(hi_, lo_) \
    (unsigned int)((((unsigned long long)(hi_) << 32) | (lo_)) >> 16)
#endif

#define FRAG_EVEN(q_) __builtin_bit_cast(short8, (uint4v){                    \
        wnd[(q_)+0], wnd[(q_)+1], wnd[(q_)+2], wnd[(q_)+3]})
#define FRAG_ODD(q_)  __builtin_bit_cast(short8, (uint4v){                    \
        ALIGN16(wnd[(q_)+1], wnd[(q_)+0]),                                    \
        ALIGN16(wnd[(q_)+2], wnd[(q_)+1]),                                    \
        ALIGN16(wnd[(q_)+3], wnd[(q_)+2]),                                    \
        ALIGN16(wnd[(q_)+4], wnd[(q_)+3])})

__global__ __launch_bounds__(256, 2)
void optical_fused_69698729279498(const float* __restrict__ x,
                                  const float* __restrict__ kern,
                                  float* __restrict__ out) {
    // 50688 B x-tile (16 ch x 11 rows x 288 B) + 10368 B kern c0-slice
    __shared__ __align__(16) unsigned short ldsb[25344 + 5184];   // 61056 B

    const int tid = threadIdx.x;
    const int l   = tid & 63;
    const int w   = tid >> 6;        // wave 0..3
    const int ph  = w & 1;           // phase half: p = 4*ph + pp
    const int cg  = w >> 1;          // channel group 0..1
    const int i0  = blockIdx.x * 2;  // first output row of tile
    const int b   = blockIdx.y;      // batch 0..7

    const int jm  = l & 15;          // A m: m = 16*rl + jm
    const int rl  = (l >> 4) & 1;    // row within 2-row tile (per-lane!)
    const int hi  = l >> 5;          // k half: tj = 8*hi + j

    unsigned int* ldsx = (unsigned int*)ldsb;
    float* kldsf = (float*)(ldsb + 25344);

    // ---- x staging: bf16 RNE + column-reversal directly into LDS.
    // Target dword index = ch*792 + (slot)*72 + d, slot = rw+1 (slots 1..10).
    // Window row rw maps to global row (i0 - 3 + rw) mod 128.
    // Row content: dword d = bf(x[(132-2d)&127]) | bf(x[(131-2d)&127])<<16
    // (matches R14 prep exactly).
    {
        const float* xb = x + ((size_t)b << 18);   // b * 16 * 16384
        int d    = tid % 72;
        int rw   = tid / 72;         // tid < 720 -> ch starts at 0
        int ch   = 0;
        int ldsi = tid + 72;         // = g + 72*ch + 72 (g = tid)
        const int gb = i0 + 125;     // grow = (i0 - 3 + rw) mod 128
#pragma unroll 5
        for (int k = 0; k < 45; ++k) {   // 45*256 = 11520 = 16*10*72 dwords
            const int grow = (gb + rw) & 127;
            const float* xp = xb + (ch << 14) + (grow << 7);
            const int c0 = (132 - 2 * d) & 127;
            const int c1 = (131 - 2 * d) & 127;
            ldsx[ldsi] = f2bf(xp[c0]) | (f2bf(xp[c1]) << 16);
            // advance g += 256 dwords = +3 rows + 40 dwords
            d += 40; if (d >= 72) { d -= 72; rw += 1; }
            rw += 3; ldsi += 256;
            if (rw >= 10) { rw -= 10; ch += 1; ldsi += 72; }
        }
    }

    // ---- kern c0-slice -> LDS (f32, 32*81 = 2592 dwords), coalesced
    {
#pragma unroll
        for (int k = 0; k < 10; ++k) {
            const int v = tid + (k << 8);
            const int o = v / 81;
            kldsf[v] = kern[o * 1296 + (v - o * 81)];
        }
        if (tid < 32) {
            const int v = 2560 + tid;
            const int o = v / 81;
            kldsf[v] = kern[o * 1296 + (v - o * 81)];
        }
    }

    __syncthreads();   // staging barrier

    // ---- B fragments: identical math to R14's bpre (f2bf of same f32s)
    short8 Bf[9];
    {
        const int o  = l & 31;
        const int kb = l >> 5;
        const float* kp = kldsf + o * 81;
#pragma unroll
        for (int ti = 0; ti < 9; ++ti) {
            unsigned int pk[4];
#pragma unroll
            for (int ee = 0; ee < 4; ++ee) {
                const int tj_a = 8 * kb + 2 * ee, tj_b = tj_a + 1;
                const float va = (tj_a <= 8) ? kp[ti * 9 + tj_a] : 0.f;
                const float vb = (tj_b <= 8) ? kp[ti * 9 + tj_b] : 0.f;
                pk[ee] = f2bf(va) | (f2bf(vb) << 16);
            }
            Bf[ti] = __builtin_bit_cast(short8, (uint4v){pk[0], pk[1], pk[2], pk[3]});
        }
    }

    float16v acc[4];
#pragma unroll
    for (int pp = 0; pp < 4; ++pp)
#pragma unroll
        for (int e = 0; e < 16; ++e) acc[pp][e] = 0.f;
    float16v zero16;
#pragma unroll
    for (int e = 0; e < 16; ++e) zero16[e] = 0.f;

    // per-lane base: chunk ti of channel c at lb + c*CHB + (8-ti)*288
    const char* lb = (const char*)ldsb
                   + (240 - 16 * jm + 16 * hi) + (1 + rl) * 288
                   + cg * 8 * CHB;

    for (int c = 0; c < 8; ++c) {
        float16v D[4];
#pragma unroll
        for (int ti = 0; ti < 9; ++ti) {
            const char* p = lb + (8 - ti) * 288;
            uint4v w0 = *(const uint4v*)p;
            uint4v w1 = *(const uint4v*)(p + 16);
            unsigned int wnd[8] = {w0.x, w0.y, w0.z, w0.w,
                                   w1.x, w1.y, w1.z, w1.w};
            short8 f0, f1, f2, f3;
            if (ph == 0) {   // p=0..3 -> frag byte offsets 14,12,10,8
                f0 = FRAG_ODD(3);  f1 = FRAG_EVEN(3);
                f2 = FRAG_ODD(2);  f3 = FRAG_EVEN(2);
            } else {         // p=4..7 -> frag byte offsets 6,4,2,0
                f0 = FRAG_ODD(1);  f1 = FRAG_EVEN(1);
                f2 = FRAG_ODD(0);  f3 = FRAG_EVEN(0);
            }
            D[0] = __builtin_amdgcn_mfma_f32_32x32x16_bf16(f0, Bf[ti], ti ? D[0] : zero16, 0, 0, 0);
            D[1] = __builtin_amdgcn_mfma_f32_32x32x16_bf16(f1, Bf[ti], ti ? D[1] : zero16, 0, 0, 0);
            D[2] = __builtin_amdgcn_mfma_f32_32x32x16_bf16(f2, Bf[ti], ti ? D[2] : zero16, 0, 0, 0);
            D[3] = __builtin_amdgcn_mfma_f32_32x32x16_bf16(f3, Bf[ti], ti ? D[3] : zero16, 0, 0, 0);
        }
#pragma unroll
        for (int pp = 0; pp < 4; ++pp)
#pragma unroll
            for (int e = 0; e < 16; ++e) acc[pp][e] += fabsf(D[pp][e]);
        lb += CHB;
    }

    // ---- cg-reduce + transpose via stride-129 LDS out-tile (conflict-free:
    //      129 = 1 mod 32), then coalesced float4 flush. Verbatim R14.
    // idx(lane,reg,p) = (r*32+o)*129 + 8*jm' + p,  r=reg>>3, o=l&31,
    // jm' = (reg&3) + 8*((reg>>2)&1) + 4*(l>>5)  [verified D map m74/m101]
    __syncthreads();   // all x-tile reads done; safe to overwrite ldsb
    float* otile = (float*)ldsb;
    const int obase_l = (l & 31) * 129 + 32 * (l >> 5) + 4 * ph;
    if (cg == 1) {
#pragma unroll
        for (int pp = 0; pp < 4; ++pp)
#pragma unroll
            for (int reg = 0; reg < 16; ++reg)
                otile[obase_l + (reg >> 3) * 4128 + 8 * (reg & 3)
                      + 64 * ((reg >> 2) & 1) + pp] = acc[pp][reg];
    }
    __syncthreads();
    if (cg == 0) {
#pragma unroll
        for (int pp = 0; pp < 4; ++pp)
#pragma unroll
            for (int reg = 0; reg < 16; ++reg) {
                const int idx = obase_l + (reg >> 3) * 4128 + 8 * (reg & 3)
                              + 64 * ((reg >> 2) & 1) + pp;
                otile[idx] += acc[pp][reg];
            }
    }
    __syncthreads();

    // flush: pair = lane (0..63), quarter = wave. Bank = (l + 4k) mod 32
    // -> 2 lanes/bank (free). Coalesced float4 global stores.
    {
        const int pair = l;            // r*32 + o
        const int q    = w;            // 32-float quarter
        const int r    = pair >> 5;
        const int o    = pair & 31;
        const float* src = otile + pair * 129 + q * 32;
        float* dstg = out + ((((size_t)(b * 32 + o)) * 128 + (i0 + r)) << 7) + q * 32;
#pragma unroll
        for (int k4 = 0; k4 < 8; ++k4) {
            float4v v = (float4v){src[4 * k4], src[4 * k4 + 1],
                                  src[4 * k4 + 2], src[4 * k4 + 3]};
            *(float4v*)&dstg[4 * k4] = v;
        }
    }
}

extern "C" void kernel_launch(void* const* d_in, const int* in_sizes, int n_in,
                              void* d_out, int out_size, void* d_ws, size_t ws_size,
                              hipStream_t stream) {
    (void)in_sizes; (void)n_in; (void)d_ws; (void)ws_size; (void)out_size;
    const float* x = (const float*)d_in[0];      // [8,16,128,128]
    const float* kern = (const float*)d_in[1];   // [32,16,9,9]
    float* out = (float*)d_out;                  // [8,32,128,128]

    // Single fused kernel; d_ws untouched (hypothesis: removes the two
    // 256 MB ws re-poison fills from the timed region).
    hipLaunchKernelGGL(optical_fused_69698729279498, dim3(64, 8), dim3(256),
                       0, stream, x, kern, out);
}